// Round 6
// baseline (297.639 us; speedup 1.0000x reference)
//
#include <hip/hip_runtime.h>
#include <hip/hip_bf16.h>

#define N 8192
#define F 256
#define KSPLIT 4
#define JBLK (N / KSPLIT)    // 2048 cols per k3 block
#define NITER (JBLK / 64)    // 32 j-tiles of 64

using s16x8 = __attribute__((ext_vector_type(8))) short;
using f32x4 = __attribute__((ext_vector_type(4))) float;

static __device__ __forceinline__ unsigned short f2bf(float f) {
  unsigned int u = __float_as_uint(f);
  unsigned int r = u + 0x7fffu + ((u >> 16) & 1u);   // RNE
  return (unsigned short)(r >> 16);
}
static __device__ __forceinline__ float bf2f(unsigned short u) {
  return __uint_as_float(((unsigned int)u) << 16);
}

// ---------------- k0: Wt[f][k] = bf16(W[k][f]) ----------------
__global__ __launch_bounds__(256) void k0_wt(const float* __restrict__ W,
                                             unsigned short* __restrict__ Wt) {
  int k = blockIdx.x;
  int f = threadIdx.x;
  Wt[f * 256 + k] = f2bf(W[k * 256 + f]);
}

// ---------------- k1: WhbT[f][j] = bf16( (h@W)[j][f] ) ----------------
__global__ __launch_bounds__(256) void k1_wh(const float* __restrict__ h,
                                             const unsigned short* __restrict__ Wt,
                                             unsigned short* __restrict__ WhbT) {
  __shared__ char lds[8192 + 32768];
  char* Alds = lds;
  char* Blds = lds + 8192;
  int t = threadIdx.x;
  int i0 = blockIdx.x * 64;
  int l = t & 63, w = t >> 6;
  int lr = l & 15, lk = l >> 4;
  f32x4 acc[4][4] = {};
  for (int kt = 0; kt < 4; ++kt) {
    int k0 = kt * 64;
    if (kt) __syncthreads();
#pragma unroll
    for (int c = 0; c < 4; ++c) {
      int flat = c * 256 + t;
      int i = flat >> 4, jc = flat & 15;
      float4 v = *reinterpret_cast<const float4*>(h + (size_t)(i0 + i) * 256 + k0 + jc * 4);
      ushort4 pk;
      pk.x = f2bf(v.x); pk.y = f2bf(v.y); pk.z = f2bf(v.z); pk.w = f2bf(v.w);
      *reinterpret_cast<ushort4*>(Alds + i * 128 + ((jc * 8) ^ ((i & 7) << 4))) = pk;
    }
#pragma unroll
    for (int c = 0; c < 8; ++c) {
      int idx = c * 256 + t;
      int fr = idx >> 3, kc = idx & 7;
      uint4 v = *reinterpret_cast<const uint4*>(Wt + fr * 256 + k0 + kc * 8);
      *reinterpret_cast<uint4*>(Blds + fr * 128 + ((kc * 16) ^ ((fr & 7) << 4))) = v;
    }
    __syncthreads();
#pragma unroll
    for (int kk = 0; kk < 2; ++kk) {
      int kofs = kk * 64 + lk * 16;
      s16x8 afr[4], bfr[4];
#pragma unroll
      for (int mf = 0; mf < 4; ++mf) {
        int ar = mf * 16 + lr;
        afr[mf] = *reinterpret_cast<const s16x8*>(Alds + ar * 128 + (kofs ^ ((ar & 7) << 4)));
      }
#pragma unroll
      for (int nf = 0; nf < 4; ++nf) {
        int br = w * 64 + nf * 16 + lr;
        bfr[nf] = *reinterpret_cast<const s16x8*>(Blds + br * 128 + (kofs ^ ((br & 7) << 4)));
      }
#pragma unroll
      for (int mf = 0; mf < 4; ++mf)
#pragma unroll
        for (int nf = 0; nf < 4; ++nf)
          acc[mf][nf] = __builtin_amdgcn_mfma_f32_16x16x32_bf16(afr[mf], bfr[nf], acc[mf][nf], 0, 0, 0);
    }
  }
#pragma unroll
  for (int mf = 0; mf < 4; ++mf) {
#pragma unroll
    for (int nf = 0; nf < 4; ++nf) {
      int f = w * 64 + nf * 16 + lr;
      int j = i0 + mf * 16 + lk * 4;
      ushort4 pk;
      pk.x = f2bf(acc[mf][nf][0]);
      pk.y = f2bf(acc[mf][nf][1]);
      pk.z = f2bf(acc[mf][nf][2]);
      pk.w = f2bf(acc[mf][nf][3]);
      *reinterpret_cast<ushort4*>(WhbT + (size_t)f * N + j) = pk;
    }
  }
}

// ---------------- k2: s1/s2 ----------------
__global__ __launch_bounds__(256) void k2_s(const unsigned short* __restrict__ WhbT,
                                            const float* __restrict__ a,
                                            float* __restrict__ s1,
                                            float* __restrict__ s2) {
  int j = blockIdx.x * 256 + threadIdx.x;
  float acc1 = 0.f, acc2 = 0.f;
#pragma unroll 8
  for (int f = 0; f < 256; ++f) {
    float v = bf2f(WhbT[(size_t)f * N + j]);
    acc1 += v * a[f];
    acc2 += v * a[256 + f];
  }
  s1[j] = acc1;
  s2[j] = acc2;
}

// ---------------- k3: adj->P(regs)->MFMA; raw barriers, counted vmcnt survives ----------------
// 256 thr (4 waves x 16 rows), M=64/block, grid (128, KSPLIT) = 512 blocks = 2/CU.
// Loop body processes TWO j-tiles (ping/pong reg sets, all static indexing).
// Barriers are raw s_barrier + lgkmcnt(0) ONLY -> adj/B prefetch stays in flight.
__global__ __launch_bounds__(256) void k3_attn(const float* __restrict__ adj,
                                               const unsigned short* __restrict__ WhbT,
                                               const float* __restrict__ s1,
                                               const float* __restrict__ s2,
                                               float* __restrict__ numw,
                                               float* __restrict__ denw) {
  __shared__ char Bbuf[2 * 32768];   // 2 x (256 f-rows x 128 B, XOR-swizzled)
  int t = threadIdx.x;
  int wv = t >> 6;
  int l = t & 63;
  int lr = l & 15, lk = l >> 4;
  int i0 = blockIdx.x * 64;
  int ks = blockIdx.y;
  int jb = ks * JBLK;
  int row = i0 + wv * 16 + lr;
  const float* arow = adj + (size_t)row * N + jb;
  const float* s2b = s2 + jb;
  float s1v = s1[row];
  int lko = lk * 8;

  f32x4 acc[16] = {};
  float dsum = 0.f;

  float4 aj0[4], aj1[4], sv0[4], sv1[4];   // ping/pong adj+s2 tile regs [kk*2+h]
  uint4 bvn[8];

  // ---- helpers (macros keep all reg indexing static) ----
#define LOAD_AJ(dst, tile)                                                      \
  {                                                                             \
    int jn = (tile) * 64;                                                       \
    _Pragma("unroll") for (int kk = 0; kk < 2; ++kk)                            \
        _Pragma("unroll") for (int h = 0; h < 2; ++h)                           \
            dst[kk * 2 + h] =                                                   \
        *reinterpret_cast<const float4*>(arow + jn + kk * 32 + lko + h * 4);    \
  }
#define LOAD_SV(dst, tile)                                                      \
  {                                                                             \
    int jn = (tile) * 64;                                                       \
    _Pragma("unroll") for (int kk = 0; kk < 2; ++kk)                            \
        _Pragma("unroll") for (int h = 0; h < 2; ++h)                           \
            dst[kk * 2 + h] =                                                   \
        *reinterpret_cast<const float4*>(s2b + jn + kk * 32 + lko + h * 4);     \
  }
#define LOAD_BV(tile)                                                           \
  {                                                                             \
    int j0 = jb + (tile) * 64;                                                  \
    _Pragma("unroll") for (int c = 0; c < 8; ++c) {                             \
      int idx = c * 256 + t;                                                    \
      int fr = idx >> 3, kc = idx & 7;                                          \
      bvn[c] = *reinterpret_cast<const uint4*>(WhbT + (size_t)fr * N + j0 + kc * 8); \
    }                                                                           \
  }
#define WRITE_BV(buf)                                                           \
  {                                                                             \
    char* Bw = Bbuf + (buf) * 32768;                                            \
    _Pragma("unroll") for (int c = 0; c < 8; ++c) {                             \
      int idx = c * 256 + t;                                                    \
      int fr = idx >> 3, kc = idx & 7;                                          \
      *reinterpret_cast<uint4*>(Bw + fr * 128 + ((kc * 16) ^ ((fr & 7) << 4))) = bvn[c]; \
    }                                                                           \
  }
#define PCOMP(ajr, svr)                                                         \
  {                                                                             \
    _Pragma("unroll") for (int kk = 0; kk < 2; ++kk) {                          \
      unsigned short u[8];                                                      \
      _Pragma("unroll") for (int h = 0; h < 2; ++h) {                           \
        float4 av = ajr[kk * 2 + h];                                            \
        float4 tv = svr[kk * 2 + h];                                            \
        float x;                                                                \
        x = s1v + tv.x; x = fmaxf(x, 0.2f * x); u[h * 4 + 0] = av.x > 0.f ? f2bf(__expf(x)) : 0; \
        x = s1v + tv.y; x = fmaxf(x, 0.2f * x); u[h * 4 + 1] = av.y > 0.f ? f2bf(__expf(x)) : 0; \
        x = s1v + tv.z; x = fmaxf(x, 0.2f * x); u[h * 4 + 2] = av.z > 0.f ? f2bf(__expf(x)) : 0; \
        x = s1v + tv.w; x = fmaxf(x, 0.2f * x); u[h * 4 + 3] = av.w > 0.f ? f2bf(__expf(x)) : 0; \
      }                                                                         \
      s16x8 af;                                                                 \
      _Pragma("unroll") for (int e = 0; e < 8; ++e) {                           \
        af[e] = (short)u[e];                                                    \
        dsum += bf2f(u[e]);                                                     \
      }                                                                         \
      afr[kk] = af;                                                             \
    }                                                                           \
  }
#define MFMA_TILE(buf)                                                          \
  {                                                                             \
    const char* Br = Bbuf + (buf) * 32768;                                      \
    _Pragma("unroll") for (int kk = 0; kk < 2; ++kk) {                          \
      int kofs = kk * 64 + lk * 16;                                             \
      _Pragma("unroll") for (int nf = 0; nf < 16; ++nf) {                       \
        int br = nf * 16 + lr;                                                  \
        s16x8 bfr = *reinterpret_cast<const s16x8*>(Br + br * 128 + (kofs ^ ((br & 7) << 4))); \
        acc[nf] = __builtin_amdgcn_mfma_f32_16x16x32_bf16(afr[kk], bfr, acc[nf], 0, 0, 0); \
      }                                                                         \
    }                                                                           \
  }
#define RAW_BARRIER()                                                           \
  {                                                                             \
    asm volatile("s_waitcnt lgkmcnt(0)" ::: "memory");                          \
    __builtin_amdgcn_s_barrier();                                               \
    __builtin_amdgcn_sched_barrier(0);                                          \
  }

  s16x8 afr[2];

  // ---- prologue: B(0)->LDS buf0; adj(0),adj(1),s2(0),s2(1) -> regs ----
  LOAD_BV(0);
  LOAD_SV(sv0, 0);
  LOAD_SV(sv1, 1);
  LOAD_AJ(aj0, 0);
  LOAD_AJ(aj1, 1);
  WRITE_BV(0);                 // compiler waits vmcnt for bvn only (counted)
  RAW_BARRIER();

  // ---- main loop: 2 tiles per body; NITER = 32 -> 16 bodies ----
  for (int k2i = 0; k2i < NITER / 2; ++k2i) {
    int e = 2 * k2i;
    // ======== even tile e: reads aj0/sv0, MFMA buf0, stages tile e+1 -> buf1
    LOAD_BV(e + 1);                          // always valid (e+1 <= NITER-1)
    PCOMP(aj0, sv0);
    if (e + 2 < NITER) { LOAD_SV(sv0, e + 2); LOAD_AJ(aj0, e + 2); }
    MFMA_TILE(0);
    WRITE_BV(1);
    RAW_BARRIER();
    // ======== odd tile o = e+1: reads aj1/sv1, MFMA buf1, stages tile e+2 -> buf0
    int o = e + 1;
    if (o + 1 < NITER) LOAD_BV(o + 1);
    PCOMP(aj1, sv1);
    if (o + 2 < NITER) { LOAD_SV(sv1, o + 2); LOAD_AJ(aj1, o + 2); }
    MFMA_TILE(1);
    if (o + 1 < NITER) WRITE_BV(0);
    RAW_BARRIER();
  }

  // ---- denominator: reduce across lk groups (j-partitions) ----
  dsum += __shfl_xor(dsum, 16);
  dsum += __shfl_xor(dsum, 32);
  if (l < 16) denw[(size_t)ks * N + row] = dsum;

  // ---- numerator partials ----
  float* nump = numw + (size_t)ks * N * F;
#pragma unroll
  for (int nf = 0; nf < 16; ++nf) {
#pragma unroll
    for (int r = 0; r < 4; ++r) {
      nump[(size_t)(i0 + wv * 16 + lk * 4 + r) * F + nf * 16 + lr] = acc[nf][r];
    }
  }
#undef LOAD_AJ
#undef LOAD_SV
#undef LOAD_BV
#undef WRITE_BV
#undef PCOMP
#undef MFMA_TILE
#undef RAW_BARRIER
}

// ---------------- k4: combine K-splits, divide, elu (float4) ----------------
__global__ __launch_bounds__(256) void k4_fin(const float* __restrict__ numw,
                                              const float* __restrict__ denw,
                                              float* __restrict__ out) {
  int idx = (blockIdx.x * 256 + threadIdx.x) * 4;
  int i = idx >> 8;
  float4 sn = {0.f, 0.f, 0.f, 0.f};
  float sd = 0.f;
#pragma unroll
  for (int ksp = 0; ksp < KSPLIT; ++ksp) {
    float4 v = *reinterpret_cast<const float4*>(numw + (size_t)ksp * N * F + idx);
    sn.x += v.x; sn.y += v.y; sn.z += v.z; sn.w += v.w;
    sd += denw[ksp * N + i];
  }
  float r = 1.f / sd;
  float4 o;
  float hp;
  hp = sn.x * r; o.x = hp > 0.f ? hp : (__expf(hp) - 1.f);
  hp = sn.y * r; o.y = hp > 0.f ? hp : (__expf(hp) - 1.f);
  hp = sn.z * r; o.z = hp > 0.f ? hp : (__expf(hp) - 1.f);
  hp = sn.w * r; o.w = hp > 0.f ? hp : (__expf(hp) - 1.f);
  *reinterpret_cast<float4*>(out + idx) = o;
}

extern "C" void kernel_launch(void* const* d_in, const int* in_sizes, int n_in,
                              void* d_out, int out_size, void* d_ws, size_t ws_size,
                              hipStream_t stream) {
  const float* h   = (const float*)d_in[0];
  const float* adj = (const float*)d_in[1];
  const float* W   = (const float*)d_in[2];
  const float* a   = (const float*)d_in[3];
  float* out = (float*)d_out;

  char* ws = (char*)d_ws;
  size_t o = 0;
  unsigned short* WhbT = (unsigned short*)(ws + o); o += (size_t)4 * 1024 * 1024;
  float* s1            = (float*)(ws + o); o += 32768;
  float* s2            = (float*)(ws + o); o += 32768;
  float* denw          = (float*)(ws + o); o += 131072;
  unsigned short* Wt   = (unsigned short*)(ws + o); o += 131072;
  float* numw          = (float*)(ws + o); o += (size_t)KSPLIT * N * F * 4;   // 32 MB

  hipLaunchKernelGGL(k0_wt, dim3(256), dim3(256), 0, stream, W, Wt);
  hipLaunchKernelGGL(k1_wh, dim3(N / 64), dim3(256), 0, stream, h, Wt, WhbT);
  hipLaunchKernelGGL(k2_s, dim3(N / 256), dim3(256), 0, stream, WhbT, a, s1, s2);
  hipLaunchKernelGGL(k3_attn, dim3(128, KSPLIT), dim3(256), 0, stream,
                     adj, WhbT, s1, s2, numw, denw);
  hipLaunchKernelGGL(k4_fin, dim3(N * F / 1024), dim3(256), 0, stream, numw, denw, out);
}

// Round 7
// 155.186 us; speedup vs baseline: 1.9180x; 1.9180x over previous
//
#include <hip/hip_runtime.h>
#include <hip/hip_bf16.h>

#define N 8192
#define F 256
#define KSPLIT 8
#define JBLK (N / KSPLIT)    // 1024 cols per k3 block
#define NITER (JBLK / 64)    // 16 j-tiles of 64
#define LOG2E 1.4426950408889634f

using s16x8 = __attribute__((ext_vector_type(8))) short;
using f32x4 = __attribute__((ext_vector_type(4))) float;

static __device__ __forceinline__ unsigned short f2bf(float f) {
  unsigned int u = __float_as_uint(f);
  unsigned int r = u + 0x7fffu + ((u >> 16) & 1u);   // RNE
  return (unsigned short)(r >> 16);
}
static __device__ __forceinline__ float bf2f(unsigned short u) {
  return __uint_as_float(((unsigned int)u) << 16);
}
static __device__ __forceinline__ void glds16(const char* g, char* l) {
  __builtin_amdgcn_global_load_lds(
      (const __attribute__((address_space(1))) unsigned int*)g,
      (__attribute__((address_space(3))) unsigned int*)l, 16, 0, 0);
}

// ---------------- k_mask: adj -> bitmask. One adj ROW (32 KB) per chunk, ----------------
// block-contiguous reads, LDS nibble transpose, coalesced word stores.
__global__ __launch_bounds__(256) void k_mask(const float* __restrict__ adj,
                                              unsigned int* __restrict__ mask) {
  __shared__ unsigned int nibw[8192];
  int t = threadIdx.x;
  for (int s = 0; s < 4; ++s) {
    size_t chunk = (size_t)s * 2048 + blockIdx.x;   // == adj row index
    const float* base = adj + chunk * 8192;
    unsigned int nib[8];
#pragma unroll
    for (int r = 0; r < 8; ++r) {
      float4 v = *reinterpret_cast<const float4*>(base + (size_t)(r * 256 + t) * 4);
      nib[r] = (v.x != 0.f ? 1u : 0u) | (v.y != 0.f ? 2u : 0u) |
               (v.z != 0.f ? 4u : 0u) | (v.w != 0.f ? 8u : 0u);
    }
    if (s) __syncthreads();
#pragma unroll
    for (int r = 0; r < 8; ++r) nibw[r * 256 + t] = nib[r];
    __syncthreads();
    unsigned int wrd = 0;
#pragma unroll
    for (int k = 0; k < 8; ++k) wrd |= nibw[t * 8 + k] << (4 * k);
    mask[chunk * 256 + t] = wrd;
  }
}

// ---------------- k0: Wt[f][k] = bf16(W[k][f]) ----------------
__global__ __launch_bounds__(256) void k0_wt(const float* __restrict__ W,
                                             unsigned short* __restrict__ Wt) {
  int k = blockIdx.x;
  int f = threadIdx.x;
  Wt[f * 256 + k] = f2bf(W[k * 256 + f]);
}

// ---------------- k1: Wh GEMM -> tiled/swizzled WhbT + fused s1,s2 (pre-scaled by log2e) ----
// WhbT tiled layout: tile tj (64 j's): byte off = tj*32768 + f*128 + ((kc*16)^((f&7)<<4)),
// kc = (j&63)>>3, +8 for odd 4-group. Tile content == the k3 LDS image (linear glds copy).
__global__ __launch_bounds__(256) void k1_wh(const float* __restrict__ h,
                                             const unsigned short* __restrict__ Wt,
                                             const float* __restrict__ a,
                                             char* __restrict__ WhbT,
                                             float* __restrict__ s1g,
                                             float* __restrict__ s2g) {
  __shared__ char lds[8192 + 32768];
  char* Alds = lds;
  char* Blds = lds + 8192;
  int t = threadIdx.x;
  int i0 = blockIdx.x * 64;
  int l = t & 63, w = t >> 6;
  int lr = l & 15, lk = l >> 4;
  f32x4 acc[4][4] = {};
  for (int kt = 0; kt < 4; ++kt) {
    int k0 = kt * 64;
    if (kt) __syncthreads();
#pragma unroll
    for (int c = 0; c < 4; ++c) {
      int flat = c * 256 + t;
      int i = flat >> 4, jc = flat & 15;
      float4 v = *reinterpret_cast<const float4*>(h + (size_t)(i0 + i) * 256 + k0 + jc * 4);
      ushort4 pk;
      pk.x = f2bf(v.x); pk.y = f2bf(v.y); pk.z = f2bf(v.z); pk.w = f2bf(v.w);
      *reinterpret_cast<ushort4*>(Alds + i * 128 + ((jc * 8) ^ ((i & 7) << 4))) = pk;
    }
#pragma unroll
    for (int c = 0; c < 8; ++c) {
      int idx = c * 256 + t;
      int fr = idx >> 3, kc = idx & 7;
      uint4 v = *reinterpret_cast<const uint4*>(Wt + fr * 256 + k0 + kc * 8);
      *reinterpret_cast<uint4*>(Blds + fr * 128 + ((kc * 16) ^ ((fr & 7) << 4))) = v;
    }
    __syncthreads();
#pragma unroll
    for (int kk = 0; kk < 2; ++kk) {
      int kofs = kk * 64 + lk * 16;
      s16x8 afr[4], bfr[4];
#pragma unroll
      for (int mf = 0; mf < 4; ++mf) {
        int ar = mf * 16 + lr;
        afr[mf] = *reinterpret_cast<const s16x8*>(Alds + ar * 128 + (kofs ^ ((ar & 7) << 4)));
      }
#pragma unroll
      for (int nf = 0; nf < 4; ++nf) {
        int br = w * 64 + nf * 16 + lr;
        bfr[nf] = *reinterpret_cast<const s16x8*>(Blds + br * 128 + (kofs ^ ((br & 7) << 4)));
      }
#pragma unroll
      for (int mf = 0; mf < 4; ++mf)
#pragma unroll
        for (int nf = 0; nf < 4; ++nf)
          acc[mf][nf] = __builtin_amdgcn_mfma_f32_16x16x32_bf16(afr[mf], bfr[nf], acc[mf][nf], 0, 0, 0);
    }
  }
  // epilogue: store in k3-ready tiled/swizzled layout
  int tj = blockIdx.x;
#pragma unroll
  for (int mf = 0; mf < 4; ++mf) {
#pragma unroll
    for (int nf = 0; nf < 4; ++nf) {
      int f = w * 64 + nf * 16 + lr;
      int jj = mf * 16 + lk * 4;
      int kc = jj >> 3, sub = (jj >> 2) & 1;
      ushort4 pk;
      pk.x = f2bf(acc[mf][nf][0]);
      pk.y = f2bf(acc[mf][nf][1]);
      pk.z = f2bf(acc[mf][nf][2]);
      pk.w = f2bf(acc[mf][nf][3]);
      *reinterpret_cast<ushort4*>(WhbT + (size_t)tj * 32768 + f * 128 +
                                  ((kc * 16) ^ ((f & 7) << 4)) + sub * 8) = pk;
    }
  }
  // fused s1/s2 from f32 accumulators
  float a1v[4], a2v[4];
#pragma unroll
  for (int nf = 0; nf < 4; ++nf) {
    int f = w * 64 + nf * 16 + lr;
    a1v[nf] = a[f];
    a2v[nf] = a[256 + f];
  }
  float* s1l = (float*)lds;
  float* s2l = s1l + 64;
  __syncthreads();
  if (t < 128) s1l[t] = 0.f;      // zeros s1l[0..63] and s2l[0..63]
  __syncthreads();
#pragma unroll
  for (int mf = 0; mf < 4; ++mf) {
#pragma unroll
    for (int r = 0; r < 4; ++r) {
      float p1 = 0.f, p2 = 0.f;
#pragma unroll
      for (int nf = 0; nf < 4; ++nf) {
        p1 += acc[mf][nf][r] * a1v[nf];
        p2 += acc[mf][nf][r] * a2v[nf];
      }
      p1 += __shfl_xor(p1, 1); p1 += __shfl_xor(p1, 2);
      p1 += __shfl_xor(p1, 4); p1 += __shfl_xor(p1, 8);
      p2 += __shfl_xor(p2, 1); p2 += __shfl_xor(p2, 2);
      p2 += __shfl_xor(p2, 4); p2 += __shfl_xor(p2, 8);
      if (lr == 0) {
        atomicAdd(&s1l[mf * 16 + lk * 4 + r], p1);
        atomicAdd(&s2l[mf * 16 + lk * 4 + r], p2);
      }
    }
  }
  __syncthreads();
  if (t < 64) {
    s1g[i0 + t] = s1l[t] * LOG2E;
    s2g[i0 + t] = s2l[t] * LOG2E;
  }
}

// ---------------- k3: mask->P(regs)->MFMA; glds B staging; counted vmcnt pipeline ----------
// 256 thr (4 waves), M=128 (2 frags/wave), grid (64, 8) = 512 blocks = 2/CU.
__global__ __launch_bounds__(256, 2) void k3_attn(const unsigned char* __restrict__ mask8,
                                                  const char* __restrict__ WhbT,
                                                  const float* __restrict__ s1,
                                                  const float* __restrict__ s2,
                                                  float* __restrict__ numw,
                                                  float* __restrict__ denw) {
  __shared__ char lds[2 * 32768 + 4096];
  char* Bbuf = lds;
  float* s2l = (float*)(lds + 65536);
  int t = threadIdx.x, w = t >> 6, l = t & 63, lr = l & 15, lk = l >> 4;
  int i0 = blockIdx.x * 128;
  int ks = blockIdx.y;
  int jb = ks * JBLK;

  // stage s2 slice (pre-scaled) to LDS
  {
    float4 v = *reinterpret_cast<const float4*>(s2 + jb + t * 4);
    *reinterpret_cast<float4*>(s2l + t * 4) = v;
  }
  int row0 = i0 + w * 32 + lr;
  int row1 = row0 + 16;
  float s1p0 = s1[row0], s1p1 = s1[row1];
  const unsigned char* mr0 = mask8 + (size_t)row0 * (N / 8) + (jb >> 3);
  const unsigned char* mr1 = mask8 + (size_t)row1 * (N / 8) + (jb >> 3);

  f32x4 acc[2][16] = {};
  float ds0 = 0.f, ds1 = 0.f;

#define GLDS_TILE(tile, buf)                                                  \
  {                                                                           \
    const char* gsrc = WhbT + ((size_t)(ks * NITER + (tile))) * 32768;        \
    char* ldst = Bbuf + (buf) * 32768;                                        \
    _Pragma("unroll") for (int c = 0; c < 8; ++c)                             \
        glds16(gsrc + c * 4096 + w * 1024 + l * 16, ldst + c * 4096 + w * 1024); \
  }

  // prologue: mask(0) then glds(0)
  unsigned int mb0a = mr0[lk], mb0b = mr0[4 + lk];
  unsigned int mb1a = mr1[lk], mb1b = mr1[4 + lk];
  GLDS_TILE(0, 0);

  for (int it = 0; it < NITER; ++it) {
    int cb = it & 1;
    bool pf = (it + 1) < NITER;
    unsigned int nb0a = 0, nb0b = 0, nb1a = 0, nb1b = 0;
    if (pf) {
      int o = (it + 1) * 8;
      nb0a = mr0[o + lk]; nb0b = mr0[o + 4 + lk];
      nb1a = mr1[o + lk]; nb1b = mr1[o + 4 + lk];
      GLDS_TILE(it + 1, cb ^ 1);
      asm volatile("s_waitcnt vmcnt(8)" ::: "memory");   // keep next glds in flight
    } else {
      asm volatile("s_waitcnt vmcnt(0)" ::: "memory");
    }
    asm volatile("s_waitcnt lgkmcnt(0)" ::: "memory");
    __builtin_amdgcn_s_barrier();                        // buf[cb] fully staged

    // ---- P-gen straight into A-fragments ----
    s16x8 af00, af01, af10, af11;
    {
      int jofs = it * 64 + lk * 8;
      float4 sa0 = *reinterpret_cast<const float4*>(s2l + jofs);
      float4 sb0 = *reinterpret_cast<const float4*>(s2l + jofs + 4);
      float4 sa1 = *reinterpret_cast<const float4*>(s2l + jofs + 32);
      float4 sb1 = *reinterpret_cast<const float4*>(s2l + jofs + 36);
#define PEL(dst, e, s1p, sv, mv, dsx)                                         \
      {                                                                       \
        float x = (s1p) + (sv); x = fmaxf(x, 0.2f * x);                       \
        float p = ((mv >> (e)) & 1u) ? exp2f(x) : 0.f;                        \
        unsigned short us = (unsigned short)((__float_as_uint(p) + 0x8000u) >> 16); \
        dsx += bf2f(us); dst[e] = (short)us;                                  \
      }
#define PFRAG(dst, s1p, sa, sb, mv, dsx)                                      \
      PEL(dst, 0, s1p, sa.x, mv, dsx) PEL(dst, 1, s1p, sa.y, mv, dsx)         \
      PEL(dst, 2, s1p, sa.z, mv, dsx) PEL(dst, 3, s1p, sa.w, mv, dsx)         \
      PEL(dst, 4, s1p, sb.x, mv, dsx) PEL(dst, 5, s1p, sb.y, mv, dsx)         \
      PEL(dst, 6, s1p, sb.z, mv, dsx) PEL(dst, 7, s1p, sb.w, mv, dsx)
      PFRAG(af00, s1p0, sa0, sb0, mb0a, ds0)
      PFRAG(af01, s1p0, sa1, sb1, mb0b, ds0)
      PFRAG(af10, s1p1, sa0, sb0, mb1a, ds1)
      PFRAG(af11, s1p1, sa1, sb1, mb1b, ds1)
#undef PFRAG
#undef PEL
    }
    // ---- MFMA: 2 kk x 16 nf, B-frag shared across the 2 row-frags ----
    const char* B = Bbuf + cb * 32768;
#pragma unroll
    for (int kk = 0; kk < 2; ++kk) {
      int kofs = kk * 64 + lk * 16;
      s16x8 a0 = kk ? af01 : af00;
      s16x8 a1 = kk ? af11 : af10;
#pragma unroll
      for (int nf = 0; nf < 16; ++nf) {
        int br = nf * 16 + lr;
        s16x8 bfr = *reinterpret_cast<const s16x8*>(B + br * 128 + (kofs ^ ((br & 7) << 4)));
        acc[0][nf] = __builtin_amdgcn_mfma_f32_16x16x32_bf16(a0, bfr, acc[0][nf], 0, 0, 0);
        acc[1][nf] = __builtin_amdgcn_mfma_f32_16x16x32_bf16(a1, bfr, acc[1][nf], 0, 0, 0);
      }
    }
    asm volatile("s_waitcnt lgkmcnt(0)" ::: "memory");
    __builtin_amdgcn_s_barrier();                        // all reads done
    mb0a = nb0a; mb0b = nb0b; mb1a = nb1a; mb1b = nb1b;
  }
#undef GLDS_TILE

  // denominators: reduce over lk groups
  ds0 += __shfl_xor(ds0, 16); ds0 += __shfl_xor(ds0, 32);
  ds1 += __shfl_xor(ds1, 16); ds1 += __shfl_xor(ds1, 32);
  if (l < 16) {
    denw[(size_t)ks * N + row0] = ds0;
    denw[(size_t)ks * N + row1] = ds1;
  }
  // numerator partials
  float* nump = numw + (size_t)ks * N * F;
#pragma unroll
  for (int mf = 0; mf < 2; ++mf) {
#pragma unroll
    for (int nf = 0; nf < 16; ++nf) {
#pragma unroll
      for (int r = 0; r < 4; ++r) {
        nump[(size_t)(i0 + w * 32 + mf * 16 + lk * 4 + r) * F + nf * 16 + lr] = acc[mf][nf][r];
      }
    }
  }
}

// ---------------- k4: combine K-splits, divide, elu (float4) ----------------
__global__ __launch_bounds__(256) void k4_fin(const float* __restrict__ numw,
                                              const float* __restrict__ denw,
                                              float* __restrict__ out) {
  int idx = (blockIdx.x * 256 + threadIdx.x) * 4;
  int i = idx >> 8;
  float4 sn = {0.f, 0.f, 0.f, 0.f};
  float sd = 0.f;
#pragma unroll
  for (int ksp = 0; ksp < KSPLIT; ++ksp) {
    float4 v = *reinterpret_cast<const float4*>(numw + (size_t)ksp * N * F + idx);
    sn.x += v.x; sn.y += v.y; sn.z += v.z; sn.w += v.w;
    sd += denw[(size_t)ksp * N + i];
  }
  float r = 1.f / sd;
  float4 o;
  float hp;
  hp = sn.x * r; o.x = hp > 0.f ? hp : (__expf(hp) - 1.f);
  hp = sn.y * r; o.y = hp > 0.f ? hp : (__expf(hp) - 1.f);
  hp = sn.z * r; o.z = hp > 0.f ? hp : (__expf(hp) - 1.f);
  hp = sn.w * r; o.w = hp > 0.f ? hp : (__expf(hp) - 1.f);
  *reinterpret_cast<float4*>(out + idx) = o;
}

extern "C" void kernel_launch(void* const* d_in, const int* in_sizes, int n_in,
                              void* d_out, int out_size, void* d_ws, size_t ws_size,
                              hipStream_t stream) {
  const float* h   = (const float*)d_in[0];
  const float* adj = (const float*)d_in[1];
  const float* W   = (const float*)d_in[2];
  const float* a   = (const float*)d_in[3];
  float* out = (float*)d_out;

  char* ws = (char*)d_ws;
  size_t o = 0;
  char* WhbT           = ws + o;                        o += (size_t)4 * 1024 * 1024;   // tiled
  float* s1            = (float*)(ws + o);              o += 32768;
  float* s2            = (float*)(ws + o);              o += 32768;
  float* denw          = (float*)(ws + o);              o += (size_t)KSPLIT * N * 4;    // 256 KB
  unsigned short* Wt   = (unsigned short*)(ws + o);     o += 131072;
  unsigned int* mask   = (unsigned int*)(ws + o);       o += (size_t)N * (N / 32) * 4;  // 8 MB
  float* numw          = (float*)(ws + o);              o += (size_t)KSPLIT * N * F * 4; // 64 MB

  hipLaunchKernelGGL(k_mask, dim3(2048), dim3(256), 0, stream, adj, mask);
  hipLaunchKernelGGL(k0_wt, dim3(256), dim3(256), 0, stream, W, Wt);
  hipLaunchKernelGGL(k1_wh, dim3(N / 64), dim3(256), 0, stream, h, Wt, a, WhbT, s1, s2);
  hipLaunchKernelGGL(k3_attn, dim3(N / 128, KSPLIT), dim3(256), 0, stream,
                     (const unsigned char*)mask, WhbT, s1, s2, numw, denw);
  hipLaunchKernelGGL(k4_fin, dim3(N * F / 1024), dim3(256), 0, stream, numw, denw, out);
}